// Round 13
// baseline (142.400 us; speedup 1.0000x reference)
//
#include <hip/hip_runtime.h>

static constexpr int D = 2048;
static constexpr int H = 4096;
static constexpr int KSTEP = 4;
static constexpr int MAX_STEPS = 64;
static constexpr float MOMC = 0.9f;

static constexpr int GRID = 256;    // 1 block/CU — proven launchable 7x.
static constexpr int BLOCK = 768;   // 12 waves/CU; bounds(768,3) -> VGPR cap ~168

// ws float layout: qc 3H | gi_l 3H | ghh 3H | ghl2 2x3D | gil 3D | dirv D
//                = 57344 floats (229376 B); barrier region 4 KB after that.
static constexpr int BAR_OFF_FLOATS = 57344;

struct Params {
  const float* query;
  const float* hg_Wih; const float* hg_Whh; const float* hg_bih; const float* hg_bhh;
  const float* hd_W; const float* hd_b;
  const float* hc_W; const float* hc_b;
  const float* lg_Wih; const float* lg_Whh; const float* lg_bih; const float* lg_bhh;
  const float* lo_W; const float* lo_b;
  const float* halt_W; const float* halt_b;
  const float* reset_W; const float* reset_b;
  const float* li_W; const float* li_b;
  float* ws; float* out;
};

__device__ __forceinline__ float sigmoidf_(float x) { return 1.f / (1.f + expf(-x)); }

// Agent-scope (LLC-coherent) accessors for all cross-block ws data.
__device__ __forceinline__ void cstore(float* p, float v) {
  __hip_atomic_store(p, v, __ATOMIC_RELAXED, __HIP_MEMORY_SCOPE_AGENT);
}
__device__ __forceinline__ float cload(const float* p) {
  return __hip_atomic_load(p, __ATOMIC_RELAXED, __HIP_MEMORY_SCOPE_AGENT);
}

// 16-leaf + root + generation tree barrier (proven R10/R11: ~2-3 us/sync).
__device__ __forceinline__ void gridbar(unsigned* bar, unsigned& mygen) {
  __syncthreads();
  if (threadIdx.x == 0) {
    unsigned* leaf = bar + (blockIdx.x & 15) * 32;
    unsigned* root = bar + 16 * 32;
    unsigned* gen  = bar + 17 * 32;
    const unsigned leafcnt = gridDim.x >> 4;
    const unsigned want = mygen + 1;
    unsigned old = __hip_atomic_fetch_add(leaf, 1u, __ATOMIC_RELEASE, __HIP_MEMORY_SCOPE_AGENT);
    if (old == leafcnt - 1u) {
      __hip_atomic_store(leaf, 0u, __ATOMIC_RELAXED, __HIP_MEMORY_SCOPE_AGENT);
      unsigned ro = __hip_atomic_fetch_add(root, 1u, __ATOMIC_ACQ_REL, __HIP_MEMORY_SCOPE_AGENT);
      if (ro == 15u) {
        __hip_atomic_store(root, 0u, __ATOMIC_RELAXED, __HIP_MEMORY_SCOPE_AGENT);
        __hip_atomic_store(gen, want, __ATOMIC_RELEASE, __HIP_MEMORY_SCOPE_AGENT);
      } else {
        while (__hip_atomic_load(gen, __ATOMIC_RELAXED, __HIP_MEMORY_SCOPE_AGENT) != want)
          __builtin_amdgcn_s_sleep(2);
      }
    } else {
      while (__hip_atomic_load(gen, __ATOMIC_RELAXED, __HIP_MEMORY_SCOPE_AGENT) != want)
        __builtin_amdgcn_s_sleep(2);
    }
  }
  mygen += 1;
  __syncthreads();
}

__device__ __forceinline__ float wred(float v) {
  #pragma unroll
  for (int off = 1; off < 64; off <<= 1) v += __shfl_xor(v, off, 64);
  return v;
}

// ---- deep-ILP dots: dot8 / dot8x2 / dot16 ONLY (dot8x3 spills — R11) ----
__device__ __forceinline__ float dot8(const float* __restrict__ row,
                                      const float* __restrict__ vec, int lane) {
  float4 a[8];
  #pragma unroll
  for (int g = 0; g < 8; ++g)
    a[g] = *reinterpret_cast<const float4*>(row + g * 256 + lane * 4);
  float s0 = 0.f, s1 = 0.f, s2 = 0.f, s3 = 0.f;
  #pragma unroll
  for (int g = 0; g < 8; g += 4) {
    float4 b0 = *reinterpret_cast<const float4*>(vec + (g + 0) * 256 + lane * 4);
    float4 b1 = *reinterpret_cast<const float4*>(vec + (g + 1) * 256 + lane * 4);
    float4 b2 = *reinterpret_cast<const float4*>(vec + (g + 2) * 256 + lane * 4);
    float4 b3 = *reinterpret_cast<const float4*>(vec + (g + 3) * 256 + lane * 4);
    s0 = fmaf(a[g+0].x, b0.x, s0); s0 = fmaf(a[g+0].y, b0.y, s0);
    s0 = fmaf(a[g+0].z, b0.z, s0); s0 = fmaf(a[g+0].w, b0.w, s0);
    s1 = fmaf(a[g+1].x, b1.x, s1); s1 = fmaf(a[g+1].y, b1.y, s1);
    s1 = fmaf(a[g+1].z, b1.z, s1); s1 = fmaf(a[g+1].w, b1.w, s1);
    s2 = fmaf(a[g+2].x, b2.x, s2); s2 = fmaf(a[g+2].y, b2.y, s2);
    s2 = fmaf(a[g+2].z, b2.z, s2); s2 = fmaf(a[g+2].w, b2.w, s2);
    s3 = fmaf(a[g+3].x, b3.x, s3); s3 = fmaf(a[g+3].y, b3.y, s3);
    s3 = fmaf(a[g+3].z, b3.z, s3); s3 = fmaf(a[g+3].w, b3.w, s3);
  }
  return (s0 + s1) + (s2 + s3);
}

__device__ __forceinline__ void dot8x2(const float* __restrict__ r0,
                                       const float* __restrict__ r1,
                                       const float* __restrict__ vec,
                                       int lane, float& o0, float& o1) {
  float4 a[8], c[8];
  #pragma unroll
  for (int g = 0; g < 8; ++g)
    a[g] = *reinterpret_cast<const float4*>(r0 + g * 256 + lane * 4);
  #pragma unroll
  for (int g = 0; g < 8; ++g)
    c[g] = *reinterpret_cast<const float4*>(r1 + g * 256 + lane * 4);
  float s0 = 0.f, s1 = 0.f, s2 = 0.f, s3 = 0.f;
  float t0 = 0.f, t1 = 0.f, t2 = 0.f, t3 = 0.f;
  #pragma unroll
  for (int g = 0; g < 8; g += 4) {
    float4 b0 = *reinterpret_cast<const float4*>(vec + (g + 0) * 256 + lane * 4);
    float4 b1 = *reinterpret_cast<const float4*>(vec + (g + 1) * 256 + lane * 4);
    float4 b2 = *reinterpret_cast<const float4*>(vec + (g + 2) * 256 + lane * 4);
    float4 b3 = *reinterpret_cast<const float4*>(vec + (g + 3) * 256 + lane * 4);
    s0 = fmaf(a[g+0].x, b0.x, s0); s0 = fmaf(a[g+0].y, b0.y, s0);
    s0 = fmaf(a[g+0].z, b0.z, s0); s0 = fmaf(a[g+0].w, b0.w, s0);
    s1 = fmaf(a[g+1].x, b1.x, s1); s1 = fmaf(a[g+1].y, b1.y, s1);
    s1 = fmaf(a[g+1].z, b1.z, s1); s1 = fmaf(a[g+1].w, b1.w, s1);
    s2 = fmaf(a[g+2].x, b2.x, s2); s2 = fmaf(a[g+2].y, b2.y, s2);
    s2 = fmaf(a[g+2].z, b2.z, s2); s2 = fmaf(a[g+2].w, b2.w, s2);
    s3 = fmaf(a[g+3].x, b3.x, s3); s3 = fmaf(a[g+3].y, b3.y, s3);
    s3 = fmaf(a[g+3].z, b3.z, s3); s3 = fmaf(a[g+3].w, b3.w, s3);
    t0 = fmaf(c[g+0].x, b0.x, t0); t0 = fmaf(c[g+0].y, b0.y, t0);
    t0 = fmaf(c[g+0].z, b0.z, t0); t0 = fmaf(c[g+0].w, b0.w, t0);
    t1 = fmaf(c[g+1].x, b1.x, t1); t1 = fmaf(c[g+1].y, b1.y, t1);
    t1 = fmaf(c[g+1].z, b1.z, t1); t1 = fmaf(c[g+1].w, b1.w, t1);
    t2 = fmaf(c[g+2].x, b2.x, t2); t2 = fmaf(c[g+2].y, b2.y, t2);
    t2 = fmaf(c[g+2].z, b2.z, t2); t2 = fmaf(c[g+2].w, b2.w, t2);
    t3 = fmaf(c[g+3].x, b3.x, t3); t3 = fmaf(c[g+3].y, b3.y, t3);
    t3 = fmaf(c[g+3].z, b3.z, t3); t3 = fmaf(c[g+3].w, b3.w, t3);
  }
  o0 = (s0 + s1) + (s2 + s3);
  o1 = (t0 + t1) + (t2 + t3);
}

__device__ __forceinline__ float dot16(const float* __restrict__ row,
                                       const float* __restrict__ vec, int lane) {
  float4 a[16];
  #pragma unroll
  for (int g = 0; g < 16; ++g)
    a[g] = *reinterpret_cast<const float4*>(row + g * 256 + lane * 4);
  float s0 = 0.f, s1 = 0.f, s2 = 0.f, s3 = 0.f;
  #pragma unroll
  for (int g = 0; g < 16; g += 4) {
    float4 b0 = *reinterpret_cast<const float4*>(vec + (g + 0) * 256 + lane * 4);
    float4 b1 = *reinterpret_cast<const float4*>(vec + (g + 1) * 256 + lane * 4);
    float4 b2 = *reinterpret_cast<const float4*>(vec + (g + 2) * 256 + lane * 4);
    float4 b3 = *reinterpret_cast<const float4*>(vec + (g + 3) * 256 + lane * 4);
    s0 = fmaf(a[g+0].x, b0.x, s0); s0 = fmaf(a[g+0].y, b0.y, s0);
    s0 = fmaf(a[g+0].z, b0.z, s0); s0 = fmaf(a[g+0].w, b0.w, s0);
    s1 = fmaf(a[g+1].x, b1.x, s1); s1 = fmaf(a[g+1].y, b1.y, s1);
    s1 = fmaf(a[g+1].z, b1.z, s1); s1 = fmaf(a[g+1].w, b1.w, s1);
    s2 = fmaf(a[g+2].x, b2.x, s2); s2 = fmaf(a[g+2].y, b2.y, s2);
    s2 = fmaf(a[g+2].z, b2.z, s2); s2 = fmaf(a[g+2].w, b2.w, s2);
    s3 = fmaf(a[g+3].x, b3.x, s3); s3 = fmaf(a[g+3].y, b3.y, s3);
    s3 = fmaf(a[g+3].z, b3.z, s3); s3 = fmaf(a[g+3].w, b3.w, s3);
  }
  return (s0 + s1) + (s2 + s3);
}

__global__ void __launch_bounds__(BLOCK, 3) reasoning_kernel(Params p) {
  const int tid = blockIdx.x * blockDim.x + threadIdx.x;
  const int nth = gridDim.x * blockDim.x;
  const int lane = threadIdx.x & 63;
  const int wid = threadIdx.x >> 6;     // 0..11
  const int gw = tid >> 6;
  const int nw = nth >> 6;              // 3072 waves at full grid

  __shared__ __align__(16) float sh_h[H];
  __shared__ __align__(16) float sh_l[D];
  __shared__ __align__(16) float sh_dir[D];
  __shared__ float sh_red[48];

  float* qc   = p.ws;            // 3H
  float* gi_l = qc + 3 * H;      // 3H
  float* ghh  = gi_l + 3 * H;    // 3H
  float* ghl2 = ghh + 3 * H;     // 2 x 3D parity ping-pong
  float* gil  = ghl2 + 6 * D;    // 3D
  float* dirv = gil + 3 * D;     // D  (also reused as reset projection)
  unsigned* bar = (unsigned*)(p.ws + BAR_OFF_FLOATS);

  for (int j = threadIdx.x; j < H; j += blockDim.x) sh_h[j] = 0.f;
  for (int j = threadIdx.x; j < D; j += blockDim.x) sh_l[j] = 0.f;
  __syncthreads();

  float cum = 0.f, rw = 0.f, mom = 0.f;
  float rawconv = 0.f, halt_h = 0.f, reset_h = 0.f;
  // output ownership: block owns rows [blk*rpb, (blk+1)*rpb); wave wid (<8)
  // owns rows blk*rpb + wid + 8k, k < rpb/8   (rpb=8 at GRID=256)
  const int rpb = D / gridDim.x;
  const int rpb8 = rpb >> 3;
  float sums[4] = {0.f, 0.f, 0.f, 0.f};
  unsigned mygen = 0;

  for (int step = 0; step < MAX_STEPS; ++step) {
    const int par = step & 1;
    const bool upd = (step & 3) == 0;
    float* ghl = ghl2 + par * 3 * D;

    // ---------------- A phase (grid-distributed dots) ----------------
    if (upd) {
      if (step == 0) {
        // 12288 rows = 6144 pairs; 2 per wave at nw=3072, balanced
        for (int t = gw * 2; t < 3 * H; t += nw * 2) {
          float o0, o1;
          dot8x2(p.hg_Wih + (size_t)t * (2 * D),
                 p.hg_Wih + (size_t)(t + 1) * (2 * D), p.query, lane, o0, o1);
          o0 = wred(o0); o1 = wred(o1);
          if (lane == 0) { cstore(qc + t, o0); cstore(qc + t + 1, o1); }
        }
      } else {
        for (int t = gw * 2; t < 3 * H; t += nw * 2) {      // gi l-part (pairs)
          float o0, o1;
          dot8x2(p.hg_Wih + (size_t)t * (2 * D) + D,
                 p.hg_Wih + (size_t)(t + 1) * (2 * D) + D, sh_l, lane, o0, o1);
          o0 = wred(o0); o1 = wred(o1);
          if (lane == 0) { cstore(gi_l + t, o0); cstore(gi_l + t + 1, o1); }
        }
        for (int t = gw; t < 3 * H; t += nw) {              // Whh @ h
          float s = wred(dot16(p.hg_Whh + (size_t)t * H, sh_h, lane));
          if (lane == 0) cstore(ghh + t, s + p.hg_bhh[t]);
        }
        for (int t = gw * 2; t < 3 * D; t += nw * 2) {      // lg_Whh (pairs)
          float o0, o1;
          dot8x2(p.lg_Whh + (size_t)t * D,
                 p.lg_Whh + (size_t)(t + 1) * D, sh_l, lane, o0, o1);
          o0 = wred(o0); o1 = wred(o1);
          if (lane == 0) { cstore(ghl + t, o0 + p.lg_bhh[t]); cstore(ghl + t + 1, o1 + p.lg_bhh[t + 1]); }
        }
      }
    } else {
      // 6144 rows = 3072 pairs: EXACTLY 1 per wave — single HBM round trip
      for (int t = gw * 2; t < 3 * D; t += nw * 2) {
        float o0, o1;
        dot8x2(p.lg_Whh + (size_t)t * D,
               p.lg_Whh + (size_t)(t + 1) * D, sh_l, lane, o0, o1);
        o0 = wred(o0); o1 = wred(o1);
        if (lane == 0) { cstore(ghl + t, o0 + p.lg_bhh[t]); cstore(ghl + t + 1, o1 + p.lg_bhh[t + 1]); }
      }
    }
    gridbar(bar, mygen);  // S1

    if (upd) {
      // ---- h-combine, block-local ----
      if (step == 0) {
        for (int i = threadIdx.x; i < H; i += blockDim.x) {
          float r = sigmoidf_(cload(qc + i) + p.hg_bih[i] + p.hg_bhh[i]);
          float z = sigmoidf_(cload(qc + H + i) + p.hg_bih[H + i] + p.hg_bhh[H + i]);
          float n = tanhf(cload(qc + 2 * H + i) + p.hg_bih[2 * H + i] + r * p.hg_bhh[2 * H + i]);
          sh_h[i] = (1.f - z) * n;
        }
      } else {
        for (int i = threadIdx.x; i < H; i += blockDim.x) {
          float r = sigmoidf_(cload(qc + i) + cload(gi_l + i) + p.hg_bih[i] + cload(ghh + i));
          float z = sigmoidf_(cload(qc + H + i) + cload(gi_l + H + i) + p.hg_bih[H + i] + cload(ghh + H + i));
          float n = tanhf(cload(qc + 2 * H + i) + cload(gi_l + 2 * H + i) + p.hg_bih[2 * H + i]
                          + r * cload(ghh + 2 * H + i));
          sh_h[i] = (1.f - z) * n + z * sh_h[i];
        }
      }
      __syncthreads();

      // ---- block-local h scalars ----
      {
        float a0 = 0.f, a1 = 0.f, a2 = 0.f;
        for (int k = threadIdx.x; k < H; k += BLOCK) {
          float hv = sh_h[k];
          a0 = fmaf(p.hc_W[k], hv, a0);
          a1 = fmaf(p.halt_W[k], hv, a1);
          a2 = fmaf(p.reset_W[k], hv, a2);
        }
        a0 = wred(a0); a1 = wred(a1); a2 = wred(a2);
        if (lane == 0) { sh_red[wid] = a0; sh_red[12 + wid] = a1; sh_red[24 + wid] = a2; }
        __syncthreads();
        float t0 = 0.f, t1 = 0.f, t2 = 0.f;
        #pragma unroll
        for (int w = 0; w < 12; ++w) { t0 += sh_red[w]; t1 += sh_red[12 + w]; t2 += sh_red[24 + w]; }
        rawconv = sigmoidf_(t0 + p.hc_b[0]);
        halt_h = t1; reset_h = t2;
        __syncthreads();
      }

      // ---- dirv dots ----
      for (int t = gw; t < D; t += nw) {
        float s = wred(dot16(p.hd_W + (size_t)t * H, sh_h, lane));
        if (lane == 0) cstore(dirv + t, tanhf(s + p.hd_b[t]));
      }
      gridbar(bar, mygen);  // S2

      for (int j = threadIdx.x; j < D; j += blockDim.x) sh_dir[j] = cload(dirv + j);
      __syncthreads();

      // ---- gil (pairs: 1 per wave, balanced) ----
      for (int t = gw * 2; t < 3 * D; t += nw * 2) {
        float o0, o1;
        dot8x2(p.lg_Wih + (size_t)t * D,
               p.lg_Wih + (size_t)(t + 1) * D, sh_dir, lane, o0, o1);
        o0 = wred(o0); o1 = wred(o1);
        if (lane == 0) { cstore(gil + t, o0 + p.lg_bih[t]); cstore(gil + t + 1, o1 + p.lg_bih[t + 1]); }
      }
      gridbar(bar, mygen);  // S3
    }

    // ---- l-combine, block-local ----
    if (step == 0) {
      for (int j = threadIdx.x; j < D; j += blockDim.x) {
        float r = sigmoidf_(cload(gil + j) + p.lg_bhh[j]);
        float z = sigmoidf_(cload(gil + D + j) + p.lg_bhh[D + j]);
        float n = tanhf(cload(gil + 2 * D + j) + r * p.lg_bhh[2 * D + j]);
        sh_l[j] = (1.f - z) * n;
      }
    } else {
      for (int j = threadIdx.x; j < D; j += blockDim.x) {
        float r = sigmoidf_(cload(gil + j) + cload(ghl + j));
        float z = sigmoidf_(cload(gil + D + j) + cload(ghl + D + j));
        float n = tanhf(cload(gil + 2 * D + j) + r * cload(ghl + 2 * D + j));
        sh_l[j] = (1.f - z) * n + z * sh_l[j];
      }
    }
    __syncthreads();

    // ---- block-local l scalars ----
    float halt_l, reset_l;
    {
      float a0 = 0.f, a1 = 0.f;
      for (int k = threadIdx.x; k < D; k += BLOCK) {
        float lv = sh_l[k];
        a0 = fmaf(p.halt_W[H + k], lv, a0);
        a1 = fmaf(p.reset_W[H + k], lv, a1);
      }
      a0 = wred(a0); a1 = wred(a1);
      if (lane == 0) { sh_red[wid] = a0; sh_red[12 + wid] = a1; }
      __syncthreads();
      float t0 = 0.f, t1 = 0.f;
      #pragma unroll
      for (int w = 0; w < 12; ++w) { t0 += sh_red[w]; t1 += sh_red[12 + w]; }
      halt_l = t0; reset_l = t1;
      __syncthreads();
    }

    // ---- scalar resolution (uniform, block-local) ----
    mom = MOMC * mom + (1.f - MOMC) * rawconv;
    float halt = sigmoidf_(halt_h + halt_l + p.halt_b[0]);
    float pp = fminf(halt, 1.f - cum);
    cum += pp; rw += pp;
    bool converged = cum > 0.95f;

    // ---- res rows: waves 0..7 of each block own rows (all blocks busy) ----
    if (wid < 8) {
      #pragma unroll
      for (int k = 0; k < 4; ++k) {
        if (k < rpb8) {
          int row = blockIdx.x * rpb + wid + 8 * k;
          float s = wred(dot8(p.lo_W + (size_t)row * D, sh_l, lane));
          sums[k] += pp * tanhf(s + p.lo_b[row]);
        }
      }
    }
    if (converged) break;

    float reset_p = sigmoidf_(reset_h + reset_l + p.reset_W[H + D] * mom + p.reset_b[0]);
    if ((reset_p > 0.7f) && (step > KSTEP)) {  // uniform across blocks
      for (int t = gw; t < D; t += nw) {
        float s = wred(dot16(p.li_W + (size_t)t * H, sh_h, lane));
        if (lane == 0) cstore(dirv + t, tanhf(s + p.li_b[t]));
      }
      gridbar(bar, mygen);
      for (int j = threadIdx.x; j < D; j += blockDim.x) sh_l[j] = cload(dirv + j);
      __syncthreads();
    }
  }

  if (wid < 8 && lane == 0) {
    float inv = 1.f / fmaxf(rw, 1e-8f);
    #pragma unroll
    for (int k = 0; k < 4; ++k) {
      if (k < rpb8) {
        int row = blockIdx.x * rpb + wid + 8 * k;
        p.out[row] = sums[k] * inv;
      }
    }
  }
}

extern "C" void kernel_launch(void* const* d_in, const int* in_sizes, int n_in,
                              void* d_out, int out_size, void* d_ws, size_t ws_size,
                              hipStream_t stream) {
  Params prm;
  prm.query   = (const float*)d_in[0];
  prm.hg_Wih  = (const float*)d_in[1];
  prm.hg_Whh  = (const float*)d_in[2];
  prm.hg_bih  = (const float*)d_in[3];
  prm.hg_bhh  = (const float*)d_in[4];
  prm.hd_W    = (const float*)d_in[5];
  prm.hd_b    = (const float*)d_in[6];
  prm.hc_W    = (const float*)d_in[7];
  prm.hc_b    = (const float*)d_in[8];
  prm.lg_Wih  = (const float*)d_in[9];
  prm.lg_Whh  = (const float*)d_in[10];
  prm.lg_bih  = (const float*)d_in[11];
  prm.lg_bhh  = (const float*)d_in[12];
  prm.lo_W    = (const float*)d_in[13];
  prm.lo_b    = (const float*)d_in[14];
  prm.halt_W  = (const float*)d_in[15];
  prm.halt_b  = (const float*)d_in[16];
  prm.reset_W = (const float*)d_in[17];
  prm.reset_b = (const float*)d_in[18];
  prm.li_W    = (const float*)d_in[19];
  prm.li_b    = (const float*)d_in[20];
  prm.ws  = (float*)d_ws;
  prm.out = (float*)d_out;

  hipMemsetAsync((char*)d_ws + (size_t)BAR_OFF_FLOATS * sizeof(float), 0, 4096, stream);

  void* args[] = { &prm };
  const int grids[3] = { GRID, GRID / 2, GRID / 4 };  // multiples of 16; rpb >= 8
  for (int g = 0; g < 3; ++g) {
    hipError_t e = hipLaunchCooperativeKernel((const void*)reasoning_kernel,
                                              dim3(grids[g]), dim3(BLOCK),
                                              args, 0, stream);
    if (e == hipSuccess) break;
  }
}

// Round 14
// 114.497 us; speedup vs baseline: 1.2437x; 1.2437x over previous
//
#include <hip/hip_runtime.h>

static constexpr int D = 2048;
static constexpr int H = 4096;
static constexpr int KSTEP = 4;
static constexpr int MAX_STEPS = 64;
static constexpr float MOMC = 0.9f;

static constexpr int GRID = 256;    // 1 block/CU — proven launchable 8x.
static constexpr int BLOCK = 512;   // bounds(512,2): VGPR 124-128, no spill (proven 3x)

// ws float layout: qc 3H | gi_l 3H | ghh 3H | ghl2 2x3D | gil 3D | dirv D
//                = 57344 floats (229376 B); barrier region 4 KB after that.
static constexpr int BAR_OFF_FLOATS = 57344;

struct Params {
  const float* query;
  const float* hg_Wih; const float* hg_Whh; const float* hg_bih; const float* hg_bhh;
  const float* hd_W; const float* hd_b;
  const float* hc_W; const float* hc_b;
  const float* lg_Wih; const float* lg_Whh; const float* lg_bih; const float* lg_bhh;
  const float* lo_W; const float* lo_b;
  const float* halt_W; const float* halt_b;
  const float* reset_W; const float* reset_b;
  const float* li_W; const float* li_b;
  float* ws; float* out;
};

__device__ __forceinline__ float sigmoidf_(float x) { return 1.f / (1.f + expf(-x)); }

// Agent-scope (LLC-coherent) accessors for all cross-block ws data.
__device__ __forceinline__ void cstore(float* p, float v) {
  __hip_atomic_store(p, v, __ATOMIC_RELAXED, __HIP_MEMORY_SCOPE_AGENT);
}
__device__ __forceinline__ float cload(const float* p) {
  return __hip_atomic_load(p, __ATOMIC_RELAXED, __HIP_MEMORY_SCOPE_AGENT);
}

// 16-leaf + root + generation tree barrier (proven R10: ~2-3 us/sync).
__device__ __forceinline__ void gridbar(unsigned* bar, unsigned& mygen) {
  __syncthreads();
  if (threadIdx.x == 0) {
    unsigned* leaf = bar + (blockIdx.x & 15) * 32;
    unsigned* root = bar + 16 * 32;
    unsigned* gen  = bar + 17 * 32;
    const unsigned leafcnt = gridDim.x >> 4;
    const unsigned want = mygen + 1;
    unsigned old = __hip_atomic_fetch_add(leaf, 1u, __ATOMIC_RELEASE, __HIP_MEMORY_SCOPE_AGENT);
    if (old == leafcnt - 1u) {
      __hip_atomic_store(leaf, 0u, __ATOMIC_RELAXED, __HIP_MEMORY_SCOPE_AGENT);
      unsigned ro = __hip_atomic_fetch_add(root, 1u, __ATOMIC_ACQ_REL, __HIP_MEMORY_SCOPE_AGENT);
      if (ro == 15u) {
        __hip_atomic_store(root, 0u, __ATOMIC_RELAXED, __HIP_MEMORY_SCOPE_AGENT);
        __hip_atomic_store(gen, want, __ATOMIC_RELEASE, __HIP_MEMORY_SCOPE_AGENT);
      } else {
        while (__hip_atomic_load(gen, __ATOMIC_RELAXED, __HIP_MEMORY_SCOPE_AGENT) != want)
          __builtin_amdgcn_s_sleep(2);
      }
    } else {
      while (__hip_atomic_load(gen, __ATOMIC_RELAXED, __HIP_MEMORY_SCOPE_AGENT) != want)
        __builtin_amdgcn_s_sleep(2);
    }
  }
  mygen += 1;
  __syncthreads();
}

__device__ __forceinline__ float wred(float v) {
  #pragma unroll
  for (int off = 1; off < 64; off <<= 1) v += __shfl_xor(v, off, 64);
  return v;
}

// ---- deep-ILP dots: dot8 / dot8x2 / dot16 ONLY (deeper spills — R11/R12) ----
__device__ __forceinline__ float dot8(const float* __restrict__ row,
                                      const float* __restrict__ vec, int lane) {
  float4 a[8];
  #pragma unroll
  for (int g = 0; g < 8; ++g)
    a[g] = *reinterpret_cast<const float4*>(row + g * 256 + lane * 4);
  float s0 = 0.f, s1 = 0.f, s2 = 0.f, s3 = 0.f;
  #pragma unroll
  for (int g = 0; g < 8; g += 4) {
    float4 b0 = *reinterpret_cast<const float4*>(vec + (g + 0) * 256 + lane * 4);
    float4 b1 = *reinterpret_cast<const float4*>(vec + (g + 1) * 256 + lane * 4);
    float4 b2 = *reinterpret_cast<const float4*>(vec + (g + 2) * 256 + lane * 4);
    float4 b3 = *reinterpret_cast<const float4*>(vec + (g + 3) * 256 + lane * 4);
    s0 = fmaf(a[g+0].x, b0.x, s0); s0 = fmaf(a[g+0].y, b0.y, s0);
    s0 = fmaf(a[g+0].z, b0.z, s0); s0 = fmaf(a[g+0].w, b0.w, s0);
    s1 = fmaf(a[g+1].x, b1.x, s1); s1 = fmaf(a[g+1].y, b1.y, s1);
    s1 = fmaf(a[g+1].z, b1.z, s1); s1 = fmaf(a[g+1].w, b1.w, s1);
    s2 = fmaf(a[g+2].x, b2.x, s2); s2 = fmaf(a[g+2].y, b2.y, s2);
    s2 = fmaf(a[g+2].z, b2.z, s2); s2 = fmaf(a[g+2].w, b2.w, s2);
    s3 = fmaf(a[g+3].x, b3.x, s3); s3 = fmaf(a[g+3].y, b3.y, s3);
    s3 = fmaf(a[g+3].z, b3.z, s3); s3 = fmaf(a[g+3].w, b3.w, s3);
  }
  return (s0 + s1) + (s2 + s3);
}

__device__ __forceinline__ void dot8x2(const float* __restrict__ r0,
                                       const float* __restrict__ r1,
                                       const float* __restrict__ vec,
                                       int lane, float& o0, float& o1) {
  float4 a[8], c[8];
  #pragma unroll
  for (int g = 0; g < 8; ++g)
    a[g] = *reinterpret_cast<const float4*>(r0 + g * 256 + lane * 4);
  #pragma unroll
  for (int g = 0; g < 8; ++g)
    c[g] = *reinterpret_cast<const float4*>(r1 + g * 256 + lane * 4);
  float s0 = 0.f, s1 = 0.f, s2 = 0.f, s3 = 0.f;
  float t0 = 0.f, t1 = 0.f, t2 = 0.f, t3 = 0.f;
  #pragma unroll
  for (int g = 0; g < 8; g += 4) {
    float4 b0 = *reinterpret_cast<const float4*>(vec + (g + 0) * 256 + lane * 4);
    float4 b1 = *reinterpret_cast<const float4*>(vec + (g + 1) * 256 + lane * 4);
    float4 b2 = *reinterpret_cast<const float4*>(vec + (g + 2) * 256 + lane * 4);
    float4 b3 = *reinterpret_cast<const float4*>(vec + (g + 3) * 256 + lane * 4);
    s0 = fmaf(a[g+0].x, b0.x, s0); s0 = fmaf(a[g+0].y, b0.y, s0);
    s0 = fmaf(a[g+0].z, b0.z, s0); s0 = fmaf(a[g+0].w, b0.w, s0);
    s1 = fmaf(a[g+1].x, b1.x, s1); s1 = fmaf(a[g+1].y, b1.y, s1);
    s1 = fmaf(a[g+1].z, b1.z, s1); s1 = fmaf(a[g+1].w, b1.w, s1);
    s2 = fmaf(a[g+2].x, b2.x, s2); s2 = fmaf(a[g+2].y, b2.y, s2);
    s2 = fmaf(a[g+2].z, b2.z, s2); s2 = fmaf(a[g+2].w, b2.w, s2);
    s3 = fmaf(a[g+3].x, b3.x, s3); s3 = fmaf(a[g+3].y, b3.y, s3);
    s3 = fmaf(a[g+3].z, b3.z, s3); s3 = fmaf(a[g+3].w, b3.w, s3);
    t0 = fmaf(c[g+0].x, b0.x, t0); t0 = fmaf(c[g+0].y, b0.y, t0);
    t0 = fmaf(c[g+0].z, b0.z, t0); t0 = fmaf(c[g+0].w, b0.w, t0);
    t1 = fmaf(c[g+1].x, b1.x, t1); t1 = fmaf(c[g+1].y, b1.y, t1);
    t1 = fmaf(c[g+1].z, b1.z, t1); t1 = fmaf(c[g+1].w, b1.w, t1);
    t2 = fmaf(c[g+2].x, b2.x, t2); t2 = fmaf(c[g+2].y, b2.y, t2);
    t2 = fmaf(c[g+2].z, b2.z, t2); t2 = fmaf(c[g+2].w, b2.w, t2);
    t3 = fmaf(c[g+3].x, b3.x, t3); t3 = fmaf(c[g+3].y, b3.y, t3);
    t3 = fmaf(c[g+3].z, b3.z, t3); t3 = fmaf(c[g+3].w, b3.w, t3);
  }
  o0 = (s0 + s1) + (s2 + s3);
  o1 = (t0 + t1) + (t2 + t3);
}

__device__ __forceinline__ float dot16(const float* __restrict__ row,
                                       const float* __restrict__ vec, int lane) {
  float4 a[16];
  #pragma unroll
  for (int g = 0; g < 16; ++g)
    a[g] = *reinterpret_cast<const float4*>(row + g * 256 + lane * 4);
  float s0 = 0.f, s1 = 0.f, s2 = 0.f, s3 = 0.f;
  #pragma unroll
  for (int g = 0; g < 16; g += 4) {
    float4 b0 = *reinterpret_cast<const float4*>(vec + (g + 0) * 256 + lane * 4);
    float4 b1 = *reinterpret_cast<const float4*>(vec + (g + 1) * 256 + lane * 4);
    float4 b2 = *reinterpret_cast<const float4*>(vec + (g + 2) * 256 + lane * 4);
    float4 b3 = *reinterpret_cast<const float4*>(vec + (g + 3) * 256 + lane * 4);
    s0 = fmaf(a[g+0].x, b0.x, s0); s0 = fmaf(a[g+0].y, b0.y, s0);
    s0 = fmaf(a[g+0].z, b0.z, s0); s0 = fmaf(a[g+0].w, b0.w, s0);
    s1 = fmaf(a[g+1].x, b1.x, s1); s1 = fmaf(a[g+1].y, b1.y, s1);
    s1 = fmaf(a[g+1].z, b1.z, s1); s1 = fmaf(a[g+1].w, b1.w, s1);
    s2 = fmaf(a[g+2].x, b2.x, s2); s2 = fmaf(a[g+2].y, b2.y, s2);
    s2 = fmaf(a[g+2].z, b2.z, s2); s2 = fmaf(a[g+2].w, b2.w, s2);
    s3 = fmaf(a[g+3].x, b3.x, s3); s3 = fmaf(a[g+3].y, b3.y, s3);
    s3 = fmaf(a[g+3].z, b3.z, s3); s3 = fmaf(a[g+3].w, b3.w, s3);
  }
  return (s0 + s1) + (s2 + s3);
}

__global__ void __launch_bounds__(BLOCK, 2) reasoning_kernel(Params p) {
  const int tid = blockIdx.x * blockDim.x + threadIdx.x;
  const int nth = gridDim.x * blockDim.x;
  const int lane = threadIdx.x & 63;
  const int wid = threadIdx.x >> 6;   // 0..7
  const int gw = tid >> 6;
  const int nw = nth >> 6;

  __shared__ __align__(16) float sh_h[H];
  __shared__ __align__(16) float sh_l[D];
  __shared__ __align__(16) float sh_dir[D];
  __shared__ float sh_red[32];

  float* qc   = p.ws;            // 3H
  float* gi_l = qc + 3 * H;      // 3H
  float* ghh  = gi_l + 3 * H;    // 3H
  float* ghl2 = ghh + 3 * H;     // 2 x 3D parity ping-pong
  float* gil  = ghl2 + 6 * D;    // 3D
  float* dirv = gil + 3 * D;     // D  (also reused as reset projection)
  unsigned* bar = (unsigned*)(p.ws + BAR_OFF_FLOATS);

  for (int j = threadIdx.x; j < H; j += blockDim.x) sh_h[j] = 0.f;
  for (int j = threadIdx.x; j < D; j += blockDim.x) sh_l[j] = 0.f;
  __syncthreads();

  float cum = 0.f, rw = 0.f, mom = 0.f;
  float rawconv = 0.f, halt_h = 0.f, reset_h = 0.f;
  // output ownership: block owns rows [blk*rpb, (blk+1)*rpb); wave wid owns
  // rows blk*rpb + wid + 8k, k < rpb/8. At GRID=256: rpb=8, 1 row per wave.
  const int rpb = D / gridDim.x;
  const int rpb8 = rpb >> 3;
  float sums[4] = {0.f, 0.f, 0.f, 0.f};
  unsigned mygen = 0;

  for (int step = 0; step < MAX_STEPS; ++step) {
    const int par = step & 1;
    const bool upd = (step & 3) == 0;
    float* ghl = ghl2 + par * 3 * D;

    // ---------------- A phase (grid-distributed dots) ----------------
    if (upd) {
      if (step == 0) {
        for (int t = gw * 2; t < 3 * H; t += nw * 2) {
          float o0, o1;
          dot8x2(p.hg_Wih + (size_t)t * (2 * D),
                 p.hg_Wih + (size_t)(t + 1) * (2 * D), p.query, lane, o0, o1);
          o0 = wred(o0); o1 = wred(o1);
          if (lane == 0) { cstore(qc + t, o0); cstore(qc + t + 1, o1); }
        }
      } else {
        for (int t = gw * 2; t < 3 * H; t += nw * 2) {      // gi l-part
          float o0, o1;
          dot8x2(p.hg_Wih + (size_t)t * (2 * D) + D,
                 p.hg_Wih + (size_t)(t + 1) * (2 * D) + D, sh_l, lane, o0, o1);
          o0 = wred(o0); o1 = wred(o1);
          if (lane == 0) { cstore(gi_l + t, o0); cstore(gi_l + t + 1, o1); }
        }
        for (int t = gw; t < 3 * H; t += nw) {              // Whh @ h
          float s = wred(dot16(p.hg_Whh + (size_t)t * H, sh_h, lane));
          if (lane == 0) cstore(ghh + t, s + p.hg_bhh[t]);
        }
        for (int t = gw * 2; t < 2 * D; t += nw * 2) {      // lg_Whh rows 0..4095 (pairs)
          float o0, o1;
          dot8x2(p.lg_Whh + (size_t)t * D,
                 p.lg_Whh + (size_t)(t + 1) * D, sh_l, lane, o0, o1);
          o0 = wred(o0); o1 = wred(o1);
          if (lane == 0) { cstore(ghl + t, o0 + p.lg_bhh[t]); cstore(ghl + t + 1, o1 + p.lg_bhh[t + 1]); }
        }
        for (int t = 2 * D + gw; t < 3 * D; t += nw) {      // rows 4096..6143 (singles)
          float s = wred(dot8(p.lg_Whh + (size_t)t * D, sh_l, lane));
          if (lane == 0) cstore(ghl + t, s + p.lg_bhh[t]);
        }
      }
    } else {
      // 2048 pairs (rows 0..4095) + 2048 singles (rows 4096..6143)
      for (int t = gw * 2; t < 2 * D; t += nw * 2) {
        float o0, o1;
        dot8x2(p.lg_Whh + (size_t)t * D,
               p.lg_Whh + (size_t)(t + 1) * D, sh_l, lane, o0, o1);
        o0 = wred(o0); o1 = wred(o1);
        if (lane == 0) { cstore(ghl + t, o0 + p.lg_bhh[t]); cstore(ghl + t + 1, o1 + p.lg_bhh[t + 1]); }
      }
      for (int t = 2 * D + gw; t < 3 * D; t += nw) {
        float s = wred(dot8(p.lg_Whh + (size_t)t * D, sh_l, lane));
        if (lane == 0) cstore(ghl + t, s + p.lg_bhh[t]);
      }
    }
    gridbar(bar, mygen);  // S1

    if (upd) {
      // ---- h-combine, block-local ----
      if (step == 0) {
        for (int i = threadIdx.x; i < H; i += blockDim.x) {
          float r = sigmoidf_(cload(qc + i) + p.hg_bih[i] + p.hg_bhh[i]);
          float z = sigmoidf_(cload(qc + H + i) + p.hg_bih[H + i] + p.hg_bhh[H + i]);
          float n = tanhf(cload(qc + 2 * H + i) + p.hg_bih[2 * H + i] + r * p.hg_bhh[2 * H + i]);
          sh_h[i] = (1.f - z) * n;
        }
      } else {
        for (int i = threadIdx.x; i < H; i += blockDim.x) {
          float r = sigmoidf_(cload(qc + i) + cload(gi_l + i) + p.hg_bih[i] + cload(ghh + i));
          float z = sigmoidf_(cload(qc + H + i) + cload(gi_l + H + i) + p.hg_bih[H + i] + cload(ghh + H + i));
          float n = tanhf(cload(qc + 2 * H + i) + cload(gi_l + 2 * H + i) + p.hg_bih[2 * H + i]
                          + r * cload(ghh + 2 * H + i));
          sh_h[i] = (1.f - z) * n + z * sh_h[i];
        }
      }
      __syncthreads();

      // ---- block-local h scalars ----
      {
        float a0 = 0.f, a1 = 0.f, a2 = 0.f;
        for (int k = threadIdx.x; k < H; k += BLOCK) {
          float hv = sh_h[k];
          a0 = fmaf(p.hc_W[k], hv, a0);
          a1 = fmaf(p.halt_W[k], hv, a1);
          a2 = fmaf(p.reset_W[k], hv, a2);
        }
        a0 = wred(a0); a1 = wred(a1); a2 = wred(a2);
        if (lane == 0) { sh_red[wid] = a0; sh_red[8 + wid] = a1; sh_red[16 + wid] = a2; }
        __syncthreads();
        float t0 = 0.f, t1 = 0.f, t2 = 0.f;
        #pragma unroll
        for (int w = 0; w < 8; ++w) { t0 += sh_red[w]; t1 += sh_red[8 + w]; t2 += sh_red[16 + w]; }
        rawconv = sigmoidf_(t0 + p.hc_b[0]);
        halt_h = t1; reset_h = t2;
        __syncthreads();
      }

      // ---- dirv dots ----
      for (int t = gw; t < D; t += nw) {
        float s = wred(dot16(p.hd_W + (size_t)t * H, sh_h, lane));
        if (lane == 0) cstore(dirv + t, tanhf(s + p.hd_b[t]));
      }
      gridbar(bar, mygen);  // S2

      for (int j = threadIdx.x; j < D; j += blockDim.x) sh_dir[j] = cload(dirv + j);
      __syncthreads();

      // ---- gil (pairs + singles, balanced) ----
      for (int t = gw * 2; t < 2 * D; t += nw * 2) {
        float o0, o1;
        dot8x2(p.lg_Wih + (size_t)t * D,
               p.lg_Wih + (size_t)(t + 1) * D, sh_dir, lane, o0, o1);
        o0 = wred(o0); o1 = wred(o1);
        if (lane == 0) { cstore(gil + t, o0 + p.lg_bih[t]); cstore(gil + t + 1, o1 + p.lg_bih[t + 1]); }
      }
      for (int t = 2 * D + gw; t < 3 * D; t += nw) {
        float s = wred(dot8(p.lg_Wih + (size_t)t * D, sh_dir, lane));
        if (lane == 0) cstore(gil + t, s + p.lg_bih[t]);
      }
      gridbar(bar, mygen);  // S3
    }

    // ---- l-combine, block-local ----
    if (step == 0) {
      for (int j = threadIdx.x; j < D; j += blockDim.x) {
        float r = sigmoidf_(cload(gil + j) + p.lg_bhh[j]);
        float z = sigmoidf_(cload(gil + D + j) + p.lg_bhh[D + j]);
        float n = tanhf(cload(gil + 2 * D + j) + r * p.lg_bhh[2 * D + j]);
        sh_l[j] = (1.f - z) * n;
      }
    } else {
      for (int j = threadIdx.x; j < D; j += blockDim.x) {
        float r = sigmoidf_(cload(gil + j) + cload(ghl + j));
        float z = sigmoidf_(cload(gil + D + j) + cload(ghl + D + j));
        float n = tanhf(cload(gil + 2 * D + j) + r * cload(ghl + 2 * D + j));
        sh_l[j] = (1.f - z) * n + z * sh_l[j];
      }
    }
    __syncthreads();

    // ---- res dots FIRST (loads overlap the l-scalars LDS reduction) ----
    float resdot[4];
    #pragma unroll
    for (int k = 0; k < 4; ++k) {
      if (k < rpb8) {
        int row = blockIdx.x * rpb + wid + 8 * k;
        float s = wred(dot8(p.lo_W + (size_t)row * D, sh_l, lane));
        resdot[k] = tanhf(s + p.lo_b[row]);
      }
    }

    // ---- block-local l scalars ----
    float halt_l, reset_l;
    {
      float a0 = 0.f, a1 = 0.f;
      for (int k = threadIdx.x; k < D; k += BLOCK) {
        float lv = sh_l[k];
        a0 = fmaf(p.halt_W[H + k], lv, a0);
        a1 = fmaf(p.reset_W[H + k], lv, a1);
      }
      a0 = wred(a0); a1 = wred(a1);
      if (lane == 0) { sh_red[wid] = a0; sh_red[8 + wid] = a1; }
      __syncthreads();
      float t0 = 0.f, t1 = 0.f;
      #pragma unroll
      for (int w = 0; w < 8; ++w) { t0 += sh_red[w]; t1 += sh_red[8 + w]; }
      halt_l = t0; reset_l = t1;
      __syncthreads();
    }

    // ---- scalar resolution (uniform, block-local) ----
    mom = MOMC * mom + (1.f - MOMC) * rawconv;
    float halt = sigmoidf_(halt_h + halt_l + p.halt_b[0]);
    float pp = fminf(halt, 1.f - cum);
    cum += pp; rw += pp;
    bool converged = cum > 0.95f;

    #pragma unroll
    for (int k = 0; k < 4; ++k) {
      if (k < rpb8) sums[k] += pp * resdot[k];
    }
    if (converged) break;

    float reset_p = sigmoidf_(reset_h + reset_l + p.reset_W[H + D] * mom + p.reset_b[0]);
    if ((reset_p > 0.7f) && (step > KSTEP)) {  // uniform across blocks
      for (int t = gw; t < D; t += nw) {
        float s = wred(dot16(p.li_W + (size_t)t * H, sh_h, lane));
        if (lane == 0) cstore(dirv + t, tanhf(s + p.li_b[t]));
      }
      gridbar(bar, mygen);
      for (int j = threadIdx.x; j < D; j += blockDim.x) sh_l[j] = cload(dirv + j);
      __syncthreads();
    }
  }

  if (lane == 0) {
    float inv = 1.f / fmaxf(rw, 1e-8f);
    #pragma unroll
    for (int k = 0; k < 4; ++k) {
      if (k < rpb8) {
        int row = blockIdx.x * rpb + wid + 8 * k;
        p.out[row] = sums[k] * inv;
      }
    }
  }
}

extern "C" void kernel_launch(void* const* d_in, const int* in_sizes, int n_in,
                              void* d_out, int out_size, void* d_ws, size_t ws_size,
                              hipStream_t stream) {
  Params prm;
  prm.query   = (const float*)d_in[0];
  prm.hg_Wih  = (const float*)d_in[1];
  prm.hg_Whh  = (const float*)d_in[2];
  prm.hg_bih  = (const float*)d_in[3];
  prm.hg_bhh  = (const float*)d_in[4];
  prm.hd_W    = (const float*)d_in[5];
  prm.hd_b    = (const float*)d_in[6];
  prm.hc_W    = (const float*)d_in[7];
  prm.hc_b    = (const float*)d_in[8];
  prm.lg_Wih  = (const float*)d_in[9];
  prm.lg_Whh  = (const float*)d_in[10];
  prm.lg_bih  = (const float*)d_in[11];
  prm.lg_bhh  = (const float*)d_in[12];
  prm.lo_W    = (const float*)d_in[13];
  prm.lo_b    = (const float*)d_in[14];
  prm.halt_W  = (const float*)d_in[15];
  prm.halt_b  = (const float*)d_in[16];
  prm.reset_W = (const float*)d_in[17];
  prm.reset_b = (const float*)d_in[18];
  prm.li_W    = (const float*)d_in[19];
  prm.li_b    = (const float*)d_in[20];
  prm.ws  = (float*)d_ws;
  prm.out = (float*)d_out;

  hipMemsetAsync((char*)d_ws + (size_t)BAR_OFF_FLOATS * sizeof(float), 0, 4096, stream);

  void* args[] = { &prm };
  const int grids[3] = { GRID, GRID / 2, GRID / 4 };  // multiples of 16; rpb >= 8
  for (int g = 0; g < 3; ++g) {
    hipError_t e = hipLaunchCooperativeKernel((const void*)reasoning_kernel,
                                              dim3(grids[g]), dim3(BLOCK),
                                              args, 0, stream);
    if (e == hipSuccess) break;
  }
}